// Round 13
// baseline (31633.768 us; speedup 1.0000x reference)
//
#include <hip/hip_runtime.h>
#include <hip/hip_fp16.h>
#include <stdint.h>

// LSTM_29042568856007: B=64, T=4096, D=256, H=256.
// Round 17: R16 with the inline-asm operand typo fixed (%8 -> %4 in
// ld64B_agent; R16 never compiled, no new evidence). Family unchanged:
// (1) prepass xg = xs@W_ih^T + b (h-independent bulk MFMA, f16 in ws);
// (2) recurrence: 4 WGs x 16 batches, ALL of W_hh on ONE CU:
//     kk0-2 pinned regs (96/lane), kk3-4 LDS (128 KB), kk5-7 L2-streamed
//     (read-only plain loads). h(t+1) through LOCAL LDS only -- zero
//     inter-WG traffic (R11-R15 proved the cross-CU relay costs ~2.8us/step
//     structurally: R14 head-start null, R15 batched poll -6%).
// ws guard: xg = CH*128KB chunks (c/h state in ws); small ws -> R15 fallback.

#define LSTM_B 64
#define LSTM_T 4096
#define LSTM_D 256
#define LSTM_H 256

#define WS_HG_OFF 0x100000u              // R15 fallback hg, 128 KB
#define WS_HST    0x120000u              // h state u32 [4g][16m][128], 32 KB
#define WS_CST    0x128000u              // c state f32 [4g][16m][256], 64 KB
#define WS_XG     0x200000u              // xg f16 pairs, CH*128 KB

typedef __attribute__((ext_vector_type(8))) _Float16 half8;
typedef __attribute__((ext_vector_type(4))) float f32x4;
typedef __attribute__((ext_vector_type(4))) uint32_t u32x4;

#define AST64(p, v) __hip_atomic_store((p), (v), __ATOMIC_RELAXED, __HIP_MEMORY_SCOPE_AGENT)
#define ALD64(p)    __hip_atomic_load((p), __ATOMIC_RELAXED, __HIP_MEMORY_SCOPE_AGENT)
#define BARLG()     asm volatile("s_waitcnt lgkmcnt(0)\n\ts_barrier" ::: "memory")

static __device__ __forceinline__ float sigmoidf_(float x) {
    return 1.0f / (1.0f + __expf(-x));
}
static __device__ __forceinline__ float tanhf_(float x) {
    float ax = fabsf(x);
    float e  = __expf(-2.0f * ax);
    float t  = (1.0f - e) / (1.0f + e);
    return copysignf(t, x);
}

// ws frags: uint4 frag[T=64][kk=16][lane=64]; layout verified R9..R15.
// slot n = T*16 + (lane&15); source gate row r = (n&3)*256 + (n>>2);
// k = 32*kk + 4*(lane>>4) + (j&3) + 16*(j>>2); k<256 -> W_hh else W_ih.
__global__ __launch_bounds__(256) void prep_frags(
    const float* __restrict__ W_ih, const float* __restrict__ W_hh,
    uint8_t* __restrict__ ws)
{
    int idx = blockIdx.x * blockDim.x + threadIdx.x;   // [0, 65536)
    uint4* Wp = (uint4*)ws;
    int lane = idx & 63;
    int kk   = (idx >> 6) & 15;
    int T    = idx >> 10;
    int n  = T * 16 + (lane & 15);
    int r  = ((n & 3) << 8) + (n >> 2);
    int kb = 32 * kk + 4 * (lane >> 4);
    uint32_t u[4];
    #pragma unroll
    for (int h = 0; h < 4; ++h) {
        uint32_t lohi[2];
        #pragma unroll
        for (int e = 0; e < 2; ++e) {
            int j = 2 * h + e;
            int k = kb + (j & 3) + 16 * (j >> 2);
            float v = (k < 256) ? W_hh[r * 256 + k] : W_ih[r * 256 + (k - 256)];
            lohi[e] = (uint32_t)__half_as_ushort(__float2half(v));
        }
        u[h] = lohi[0] | (lohi[1] << 16);
    }
    Wp[idx] = make_uint4(u[0], u[1], u[2], u[3]);
    if (idx < 32768) ((uint32_t*)(ws + WS_HG_OFF))[idx] = 0u;  // R15 hg
    if (idx < 24576) ((uint32_t*)(ws + WS_HST))[idx]   = 0u;  // h+c state
}

// ================= prepass: xg[t][T][lane] = 2xu32 f16 pairs ===============
// grid 32 = gg(4 groups of 16 batches) x cs(8 tile-slices of 8), 256 thr.
__global__ __launch_bounds__(256, 1) void xg_prep(
    const float* __restrict__ xs, const float* __restrict__ bias_g,
    uint8_t* __restrict__ ws, int tbase, int CH)
{
    const int tid = threadIdx.x;
    const int l   = tid & 63;
    const int wv  = tid >> 6;            // 0..3
    const int gg  = blockIdx.x >> 3;
    const int cs  = blockIdx.x & 7;
    const int T0  = cs * 8 + wv * 2;     // this wave: tiles T0, T0+1

    const uint4* WF = (const uint4*)ws;
    uint2* xg = (uint2*)(ws + WS_XG) + (size_t)gg * CH * 64 * 64;

    __shared__ __align__(16) uint8_t hxp[8 * 64 * 16];   // x A-frags, 8 KB

    // pinned W_ih B-frags (kk 8..15 of Wp) for 2 tiles: 64 regs
    uint4 wfx[2][8];
    #pragma unroll
    for (int t2 = 0; t2 < 2; ++t2)
        #pragma unroll
        for (int kk = 0; kk < 8; ++kk)
            wfx[t2][kk] = WF[((T0 + t2) * 16 + 8 + kk) * 64 + l];
    #pragma unroll
    for (int t2 = 0; t2 < 2; ++t2)
        #pragma unroll
        for (int kk = 0; kk < 8; ++kk)
            asm volatile("" : "+v"(wfx[t2][kk].x), "+v"(wfx[t2][kk].y),
                              "+v"(wfx[t2][kk].z), "+v"(wfx[t2][kk].w));

    float biasv[2];
    #pragma unroll
    for (int t2 = 0; t2 < 2; ++t2) {
        int slot = (T0 + t2) * 16 + (l & 15);
        biasv[t2] = bias_g[((slot & 3) << 8) + (slot >> 2)];
    }

    // x staging: thread covers (m_s in [0,16), cols d0..d0+15)
    const int m_s = tid >> 4;
    const int d0  = (tid & 15) * 16;
    const float* xrow = xs + (size_t)(16 * gg + m_s) * LSTM_T * LSTM_D + d0;

    float4 xb[4];
    #pragma unroll
    for (int i = 0; i < 4; ++i)
        xb[i] = ((const float4*)(xrow + (size_t)tbase * LSTM_D))[i];

    for (int tloc = 0; tloc < CH; ++tloc) {
        // stage x(t) A-frags (R15-verified swizzle; k0 = d0+4i, kk in [0,8))
        #pragma unroll
        for (int i = 0; i < 4; ++i) {
            float4 xv = xb[i];
            __half2 h0 = __floats2half2_rn(xv.x, xv.y);
            __half2 h1 = __floats2half2_rn(xv.z, xv.w);
            uint64_t v = (uint64_t)__builtin_bit_cast(uint32_t, h0)
                       | ((uint64_t)__builtin_bit_cast(uint32_t, h1) << 32);
            int k0 = d0 + 4 * i;
            int kk = k0 >> 5, off = k0 & 31;
            int q = (off & 15) >> 2, hi = off >> 4;
            int slot = (m_s + 16 * q) ^ ((2 * kk) & 63);
            *(uint64_t*)(hxp + kk * 1024 + slot * 16 + hi * 8) = v;
        }
        {   // prefetch next t (clamped)
            int tn = tbase + tloc + 1; if (tn > LSTM_T - 1) tn = LSTM_T - 1;
            const float4* nx = (const float4*)(xrow + (size_t)tn * LSTM_D);
            #pragma unroll
            for (int i = 0; i < 4; ++i) xb[i] = nx[i];
        }
        BARLG();

        uint4 af[8];
        #pragma unroll
        for (int kk = 0; kk < 8; ++kk)
            af[kk] = *(const uint4*)(hxp + (kk * 64 + (l ^ ((2 * kk) & 63))) * 16);

        f32x4 acc[2];
        #pragma unroll
        for (int t2 = 0; t2 < 2; ++t2)
            acc[t2] = (f32x4){biasv[t2], biasv[t2], biasv[t2], biasv[t2]};
        #pragma unroll
        for (int kk = 0; kk < 8; ++kk) {
            half8 a = __builtin_bit_cast(half8, af[kk]);
            #pragma unroll
            for (int t2 = 0; t2 < 2; ++t2)
                acc[t2] = __builtin_amdgcn_mfma_f32_16x16x32_f16(
                    a, __builtin_bit_cast(half8, wfx[t2][kk]), acc[t2], 0, 0, 0);
        }
        #pragma unroll
        for (int t2 = 0; t2 < 2; ++t2) {
            __half2 lo = __floats2half2_rn(acc[t2].x, acc[t2].y);
            __half2 hi = __floats2half2_rn(acc[t2].z, acc[t2].w);
            xg[(((size_t)tloc) * 64 + T0 + t2) * 64 + l] =
                make_uint2(__builtin_bit_cast(uint32_t, lo),
                           __builtin_bit_cast(uint32_t, hi));
        }
        BARLG();   // hxp reusable
    }
}

// ================= recurrence: 4 WGs x 16 batches, single-CU W_hh ==========
__global__ __launch_bounds__(512, 2) void lstm_rec(
    uint8_t* __restrict__ ws, float* __restrict__ out, int CH, int final_ch)
{
    const int tid = threadIdx.x;
    const int l   = tid & 63;
    const int wv  = tid >> 6;            // wave 0..7, owns tiles 8wv..8wv+7
    const int gg  = blockIdx.x;          // batches 16gg..16gg+15

    const uint4* WF = (const uint4*)ws;
    uint32_t* hstate = (uint32_t*)(ws + WS_HST) + (size_t)gg * 16 * 128;
    float*    cstate = (float*)(ws + WS_CST)    + (size_t)gg * 16 * 256;
    const uint2* xg  = (const uint2*)(ws + WS_XG) + (size_t)gg * CH * 64 * 64;

    __shared__ uint4 wl[2 * 64 * 64];                 // W_hh kk3,4: 128 KB
    __shared__ __align__(16) uint8_t hA[8 * 64 * 16]; // h A-frags: 8 KB

    // LDS W tier (kk 3..4): 512 thr x 16 uint4
    #pragma unroll
    for (int j2 = 0; j2 < 16; ++j2) {
        int idx = j2 * 512 + tid;        // (kkL*64 + T)*64 + l
        int kkL = idx >> 12, T = (idx >> 6) & 63, ll = idx & 63;
        wl[idx] = WF[(T * 16 + 3 + kkL) * 64 + ll];
    }

    // pinned W tier (kk 0..2) for this wave's 8 tiles: 96 regs
    uint4 wfh[8][3];
    #pragma unroll
    for (int tl = 0; tl < 8; ++tl) {
        int T = wv * 8 + tl;
        #pragma unroll
        for (int kk = 0; kk < 3; ++kk)
            wfh[tl][kk] = WF[(T * 16 + kk) * 64 + l];
    }
    #pragma unroll
    for (int tl = 0; tl < 8; ++tl)
        #pragma unroll
        for (int kk = 0; kk < 3; ++kk)
            asm volatile("" : "+v"(wfh[tl][kk].x), "+v"(wfh[tl][kk].y),
                              "+v"(wfh[tl][kk].z), "+v"(wfh[tl][kk].w));

    // per-lane ew constants (R9/R15-verified D layout)
    const int  c2   = l & 3;
    const int  qa   = l >> 4;
    const bool c2b0 = (c2 & 1) != 0, c2b1 = (c2 & 2) != 0;
    const int  m_ew = 4 * qa + c2;       // batch row in [0,16)
    int jj[8];
    #pragma unroll
    for (int tl = 0; tl < 8; ++tl) {
        int slot = (wv * 8 + tl) * 16 + (l & 15);
        jj[tl] = slot >> 2;              // h-col [0,256)
    }

    // restore h(t0) into hA (R15-verified scatter; m in [0,16))
    if (tid < 256) {
        int m_s = tid >> 4, d0 = (tid & 15) * 16;
        const uint32_t* hr = hstate + m_s * 128 + (d0 >> 1);
        #pragma unroll
        for (int i = 0; i < 8; ++i) {
            uint32_t pr = hr[i];
            int k0 = d0 + 2 * i;
            int kk = k0 >> 5, off = k0 & 31;
            int q = (off & 15) >> 2, hi = off >> 4;
            int slot = (m_s + 16 * q) ^ ((2 * kk) & 63);
            *(uint32_t*)(hA + kk * 1024 + slot * 16 + hi * 8 + ((off & 3) << 1)) = pr;
        }
    }
    float c[8];
    #pragma unroll
    for (int tl = 0; tl < 8; ++tl) c[tl] = cstate[m_ew * 256 + jj[tl]];

    BARLG();   // wl + hA ready

    // prologue: xg(0)
    uint2 xgv[8];
    #pragma unroll
    for (int tl = 0; tl < 8; ++tl)
        xgv[tl] = xg[((size_t)0 * 64 + wv * 8 + tl) * 64 + l];

    uint32_t hpair[8];

    for (int tloc = 0; tloc < CH; ++tloc) {
        // A-frags h(t)
        uint4 af[8];
        #pragma unroll
        for (int kk = 0; kk < 8; ++kk)
            af[kk] = *(const uint4*)(hA + (kk * 64 + (l ^ ((2 * kk) & 63))) * 16);

        const bool fin = final_ch && (tloc == CH - 1);

        // two half-passes of 4 tiles (caps live registers)
        #pragma unroll
        for (int hp = 0; hp < 2; ++hp) {
            const int base = hp * 4;
            // stream kk5,6 for these tiles (plain cached loads, L2-resident W)
            uint4 s5[4], s6[4];
            #pragma unroll
            for (int i = 0; i < 4; ++i) {
                int T = wv * 8 + base + i;
                s5[i] = WF[(T * 16 + 5) * 64 + l];
                s6[i] = WF[(T * 16 + 6) * 64 + l];
            }
            // acc init from xg
            f32x4 acc[4];
            #pragma unroll
            for (int i = 0; i < 4; ++i) {
                uint2 v = xgv[base + i];
                float2 f0 = __half22float2(__builtin_bit_cast(__half2, v.x));
                float2 f1 = __half22float2(__builtin_bit_cast(__half2, v.y));
                acc[i] = (f32x4){f0.x, f0.y, f1.x, f1.y};
            }
            // pinned kk0..2
            #pragma unroll
            for (int kk = 0; kk < 3; ++kk) {
                half8 a = __builtin_bit_cast(half8, af[kk]);
                #pragma unroll
                for (int i = 0; i < 4; ++i)
                    acc[i] = __builtin_amdgcn_mfma_f32_16x16x32_f16(
                        a, __builtin_bit_cast(half8, wfh[base + i][kk]), acc[i], 0, 0, 0);
            }
            // stream kk7 issue
            uint4 s7[4];
            #pragma unroll
            for (int i = 0; i < 4; ++i)
                s7[i] = WF[((wv * 8 + base + i) * 16 + 7) * 64 + l];
            // LDS kk3,4 (inline reads)
            #pragma unroll
            for (int kkL = 0; kkL < 2; ++kkL) {
                half8 a = __builtin_bit_cast(half8, af[3 + kkL]);
                #pragma unroll
                for (int i = 0; i < 4; ++i) {
                    uint4 wb = wl[(kkL * 64 + wv * 8 + base + i) * 64 + l];
                    acc[i] = __builtin_amdgcn_mfma_f32_16x16x32_f16(
                        a, __builtin_bit_cast(half8, wb), acc[i], 0, 0, 0);
                }
            }
            // streamed kk5,6,7
            {
                half8 a5 = __builtin_bit_cast(half8, af[5]);
                half8 a6 = __builtin_bit_cast(half8, af[6]);
                half8 a7 = __builtin_bit_cast(half8, af[7]);
                #pragma unroll
                for (int i = 0; i < 4; ++i)
                    acc[i] = __builtin_amdgcn_mfma_f32_16x16x32_f16(
                        a5, __builtin_bit_cast(half8, s5[i]), acc[i], 0, 0, 0);
                #pragma unroll
                for (int i = 0; i < 4; ++i)
                    acc[i] = __builtin_amdgcn_mfma_f32_16x16x32_f16(
                        a6, __builtin_bit_cast(half8, s6[i]), acc[i], 0, 0, 0);
                #pragma unroll
                for (int i = 0; i < 4; ++i)
                    acc[i] = __builtin_amdgcn_mfma_f32_16x16x32_f16(
                        a7, __builtin_bit_cast(half8, s7[i]), acc[i], 0, 0, 0);
            }
            // ew (R15-verified gather) + pack
            #pragma unroll
            for (int i = 0; i < 4; ++i) {
                int tl = base + i;
                f32x4 a = acc[i];
                float s01  = c2b0 ? a.y : a.x;
                float s23  = c2b0 ? a.w : a.z;
                float s01b = c2b0 ? a.x : a.y;
                float s23b = c2b0 ? a.z : a.w;
                float own = c2b1 ? s23  : s01;
                float v1  = c2b1 ? s23b : s01b;
                float v2  = c2b1 ? s01  : s23;
                float v3  = c2b1 ? s01b : s23b;
                float r1 = __shfl_xor(v1, 1, 64);
                float r2 = __shfl_xor(v2, 2, 64);
                float r3 = __shfl_xor(v3, 3, 64);
                float gi = c2b1 ? (c2b0 ? r3 : r2) : (c2b0 ? r1 : own);
                float gf = c2b1 ? (c2b0 ? r2 : r3) : (c2b0 ? own : r1);
                float gg2 = c2b1 ? (c2b0 ? r1 : own) : (c2b0 ? r3 : r2);
                float go = c2b1 ? (c2b0 ? own : r1) : (c2b0 ? r2 : r3);
                float cc = c[tl];
                cc = sigmoidf_(gf) * cc + sigmoidf_(gi) * tanhf_(gg2);
                float hh = sigmoidf_(go) * tanhf_(cc);
                c[tl] = cc;
                uint32_t u  = (uint32_t)__half_as_ushort(__float2half(hh));
                uint32_t up = (uint32_t)__shfl_xor((int)u, 4, 64);
                hpair[tl] = (u & 0xffffu) | (up << 16);
                if (fin) {
                    int b = 16 * gg + m_ew;
                    out[b * LSTM_H + jj[tl]]                        = hh;
                    out[LSTM_B * LSTM_H + b * LSTM_H + jj[tl]]      = cc;
                }
            }
        }

        // prefetch xg(t+1)
        if (tloc + 1 < CH) {
            #pragma unroll
            for (int tl = 0; tl < 8; ++tl)
                xgv[tl] = xg[((size_t)(tloc + 1) * 64 + wv * 8 + tl) * 64 + l];
        }

        BARLG();   // all A-reads of h(t) complete
        // write h(t+1) into hA (same scatter math, m=m_ew, k0=jj even)
        if ((l & 4) == 0) {
            #pragma unroll
            for (int tl = 0; tl < 8; ++tl) {
                int k0 = jj[tl];
                int kk = k0 >> 5, off = k0 & 31;
                int q = (off & 15) >> 2, hi = off >> 4;
                int slot = (m_ew + 16 * q) ^ ((2 * kk) & 63);
                *(uint32_t*)(hA + kk * 1024 + slot * 16 + hi * 8 + ((off & 3) << 1)) = hpair[tl];
            }
        }
        BARLG();   // h(t+1) visible
    }

    // save state for next chunk
    if ((l & 4) == 0) {
        #pragma unroll
        for (int tl = 0; tl < 8; ++tl)
            hstate[m_ew * 128 + (jj[tl] >> 1)] = hpair[tl];
    }
    #pragma unroll
    for (int tl = 0; tl < 8; ++tl) cstate[m_ew * 256 + jj[tl]] = c[tl];
}

// ===================== R15 fallback (verified, 11.8 ms) ====================
static __device__ __forceinline__ void ld64B_agent(const uint64_t* p, uint64_t* v) {
    u32x4 a, b, cq, d;
    asm volatile(
        "global_load_dwordx4 %0, %4, off sc1\n\t"
        "global_load_dwordx4 %1, %4, off offset:16 sc1\n\t"
        "global_load_dwordx4 %2, %4, off offset:32 sc1\n\t"
        "global_load_dwordx4 %3, %4, off offset:48 sc1\n\t"
        "s_waitcnt vmcnt(0)"
        : "=&v"(a), "=&v"(b), "=&v"(cq), "=&v"(d)
        : "v"(p) : "memory");
    v[0] = ((uint64_t)a.y << 32) | a.x;   v[1] = ((uint64_t)a.w << 32) | a.z;
    v[2] = ((uint64_t)b.y << 32) | b.x;   v[3] = ((uint64_t)b.w << 32) | b.z;
    v[4] = ((uint64_t)cq.y << 32) | cq.x; v[5] = ((uint64_t)cq.w << 32) | cq.z;
    v[6] = ((uint64_t)d.y << 32) | d.x;   v[7] = ((uint64_t)d.w << 32) | d.z;
}

__global__ __launch_bounds__(256, 1) void lstm_r15(
    const float* __restrict__ xs, const float* __restrict__ bias_g,
    uint8_t* __restrict__ ws, float* __restrict__ out)
{
    const int tid = threadIdx.x;
    const int l   = tid & 63;
    const int w   = tid >> 6;
    const int g   = blockIdx.x & 7;
    const int p   = blockIdx.x >> 3;

    const uint4* WF = (const uint4*)ws;
    uint64_t* hg64  = (uint64_t*)(ws + WS_HG_OFF);

    __shared__ uint4 hx[16 * 64];

    uint4 wf[4][16];
    #pragma unroll
    for (int tl = 0; tl < 4; ++tl) {
        int T = p * 16 + w * 4 + tl;
        #pragma unroll
        for (int kk = 0; kk < 16; ++kk)
            wf[tl][kk] = WF[(T * 16 + kk) * 64 + l];
    }
    #pragma unroll
    for (int tl = 0; tl < 4; ++tl)
        #pragma unroll
        for (int kk = 0; kk < 16; ++kk)
            asm volatile("" : "+v"(wf[tl][kk].x), "+v"(wf[tl][kk].y),
                              "+v"(wf[tl][kk].z), "+v"(wf[tl][kk].w));

    const int  c2   = l & 3;
    const int  qa   = l >> 4;
    const bool c2b0 = (c2 & 1) != 0, c2b1 = (c2 & 2) != 0;
    const int  m_ew = 4 * qa + c2;
    float bias[4];
    int   jj[4];
    #pragma unroll
    for (int tl = 0; tl < 4; ++tl) {
        int T    = p * 16 + w * 4 + tl;
        int slot = T * 16 + (l & 15);
        int r    = ((slot & 3) << 8) + (slot >> 2);
        bias[tl] = bias_g[r];
        jj[tl]   = slot >> 2;
    }

    const int m_s = tid >> 4;
    const int d0  = (tid & 15) * 16;
    const float* xrow = xs + (size_t)(8 * g + (m_s & 7)) * LSTM_T * LSTM_D + d0;

    hx[tid]       = make_uint4(0, 0, 0, 0);
    hx[tid + 256] = make_uint4(0, 0, 0, 0);
    hx[tid + 512] = make_uint4(0, 0, 0, 0);
    hx[tid + 768] = make_uint4(0, 0, 0, 0);
    float4 xb[2][4];
    if (m_s < 8) {
        #pragma unroll
        for (int i = 0; i < 4; ++i) {
            float4 xv = ((const float4*)xrow)[i];
            __half2 h0 = __floats2half2_rn(xv.x, xv.y);
            __half2 h1 = __floats2half2_rn(xv.z, xv.w);
            uint64_t v = (uint64_t)__builtin_bit_cast(uint32_t, h0)
                       | ((uint64_t)__builtin_bit_cast(uint32_t, h1) << 32);
            int k0 = 256 + d0 + 4 * i;
            int kk = k0 >> 5, off = k0 & 31;
            int q = (off & 15) >> 2, hi = off >> 4;
            int slot = (m_s + 16 * q) ^ ((2 * kk) & 63);
            *(uint64_t*)((uint8_t*)hx + kk * 1024 + slot * 16 + hi * 8) = v;
        }
        #pragma unroll
        for (int i = 0; i < 4; ++i) xb[0][i] = ((const float4*)(xrow + (size_t)1 * LSTM_D))[i];
        #pragma unroll
        for (int i = 0; i < 4; ++i) xb[1][i] = ((const float4*)(xrow + (size_t)2 * LSTM_D))[i];
    }
    BARLG();

    f32x4 accA[4], accB[4];
    {
        uint4 afx[8];
        #pragma unroll
        for (int kx = 0; kx < 8; ++kx) {
            int kk = kx + 8;
            afx[kx] = hx[kk * 64 + (l ^ ((2 * kk) & 63))];
        }
        #pragma unroll
        for (int tl = 0; tl < 4; ++tl)
            accA[tl] = (f32x4){bias[tl], bias[tl], bias[tl], bias[tl]};
        #pragma unroll
        for (int kx = 0; kx < 8; ++kx) {
            half8 a = __builtin_bit_cast(half8, afx[kx]);
            #pragma unroll
            for (int tl = 0; tl < 4; ++tl)
                accA[tl] = __builtin_amdgcn_mfma_f32_16x16x32_f16(
                    a, __builtin_bit_cast(half8, wf[tl][kx + 8]), accA[tl], 0, 0, 0);
        }
    }

    float cst[4] = {0, 0, 0, 0}, hst[4] = {0, 0, 0, 0};

#define STEP(T_, PAR, ACC_C, ACC_N) do {                                            \
    uint4 afh[8];                                                                   \
    _Pragma("unroll")                                                               \
    for (int kk = 0; kk < 8; ++kk)                                                  \
        afh[kk] = hx[kk * 64 + (l ^ ((2 * kk) & 63))];                              \
    _Pragma("unroll")                                                               \
    for (int kk = 0; kk < 8; ++kk) {                                                \
        half8 a = __builtin_bit_cast(half8, afh[kk]);                               \
        _Pragma("unroll")                                                           \
        for (int tl = 0; tl < 4; ++tl)                                              \
            ACC_C[tl] = __builtin_amdgcn_mfma_f32_16x16x32_f16(                     \
                a, __builtin_bit_cast(half8, wf[tl][kk]), ACC_C[tl], 0, 0, 0);      \
    }                                                                               \
    uint32_t hpair[4];                                                              \
    _Pragma("unroll")                                                               \
    for (int tl = 0; tl < 4; ++tl) {                                                \
        f32x4 a = ACC_C[tl];                                                        \
        float s01  = c2b0 ? a.y : a.x;                                              \
        float s23  = c2b0 ? a.w : a.z;                                              \
        float s01b = c2b0 ? a.x : a.y;                                              \
        float s23b = c2b0 ? a.z : a.w;                                              \
        float own = c2b1 ? s23  : s01;                                              \
        float v1  = c2b1 ? s23b : s01b;                                             \
        float v2  = c2b1 ? s01  : s23;                                              \
        float v3  = c2b1 ? s01b : s23b;                                             \
        float r1 = __shfl_xor(v1, 1, 64);                                           \
        float r2 = __shfl_xor(v2, 2, 64);                                           \
        float r3 = __shfl_xor(v3, 3, 64);                                           \
        float gi = c2b1 ? (c2b0 ? r3 : r2) : (c2b0 ? r1 : own);                     \
        float gf = c2b1 ? (c2b0 ? r2 : r3) : (c2b0 ? own : r1);                     \
        float gg = c2b1 ? (c2b0 ? r1 : own) : (c2b0 ? r3 : r2);                     \
        float go = c2b1 ? (c2b0 ? own : r1) : (c2b0 ? r2 : r3);                     \
        float cc = cst[tl];                                                         \
        cc = sigmoidf_(gf) * cc + sigmoidf_(gi) * tanhf_(gg);                       \
        float hh = sigmoidf_(go) * tanhf_(cc);                                      \
        cst[tl] = cc; hst[tl] = hh;                                                 \
        uint32_t u  = (uint32_t)__half_as_ushort(__float2half(hh));                 \
        uint32_t up = (uint32_t)__shfl_xor((int)u, 4, 64);                          \
        hpair[tl] = (u & 0xffffu) | (up << 16);                                     \
    }                                                                               \
    {                                                                               \
        const int buf = (PAR) ^ 1;                                                  \
        if (l < 32 && (l & 4) == 0) {                                               \
            uint64_t* hgrow = hg64 + (((size_t)g * 2 + buf) * 8 + m_ew) * 128;      \
            const uint64_t tagw = ((uint64_t)(uint32_t)(T_ + 1)) << 32;             \
            _Pragma("unroll")                                                       \
            for (int tl = 0; tl < 4; ++tl)                                          \
                AST64(&hgrow[jj[tl] >> 1], tagw | (uint64_t)hpair[tl]);             \
        }                                                                           \
        if (m_s < 8) {                                                              \
            _Pragma("unroll")                                                       \
            for (int i = 0; i < 4; ++i) {                                           \
                float4 xv = xb[PAR][i];                                             \
                __half2 h0 = __floats2half2_rn(xv.x, xv.y);                         \
                __half2 h1 = __floats2half2_rn(xv.z, xv.w);                         \
                uint64_t v = (uint64_t)__builtin_bit_cast(uint32_t, h0)             \
                           | ((uint64_t)__builtin_bit_cast(uint32_t, h1) << 32);    \
                int k0 = 256 + d0 + 4 * i;                                          \
                int kk = k0 >> 5, off = k0 & 31;                                    \
                int q = (off & 15) >> 2, hi = off >> 4;                             \
                int slot = (m_s + 16 * q) ^ ((2 * kk) & 63);                        \
                *(uint64_t*)((uint8_t*)hx + kk * 1024 + slot * 16 + hi * 8) = v;    \
            }                                                                       \
            int tn = (T_ + 3 < LSTM_T) ? T_ + 3 : T_;                               \
            const float4* nx = (const float4*)(xrow + (size_t)tn * LSTM_D);         \
            _Pragma("unroll")                                                       \
            for (int i = 0; i < 4; ++i) xb[PAR][i] = nx[i];                         \
        }                                                                           \
        BARLG();                                                                    \
        uint4 afx[8];                                                               \
        _Pragma("unroll")                                                           \
        for (int kx = 0; kx < 8; ++kx) {                                            \
            int kk = kx + 8;                                                        \
            afx[kx] = hx[kk * 64 + (l ^ ((2 * kk) & 63))];                          \
        }                                                                           \
        if (m_s < 8) {                                                              \
            const uint32_t tgt = (uint32_t)(T_ + 1);                                \
            uint64_t* hgr = hg64 + (((size_t)g * 2 + buf) * 8 + m_s) * 128          \
                          + (d0 >> 1);                                              \
            uint64_t hv[8];                                                         \
            ld64B_agent(hgr, hv);                                                   \
            int spin = 0;                                                           \
            while (true) {                                                          \
                bool ok = true;                                                     \
                _Pragma("unroll")                                                   \
                for (int i = 0; i < 8; ++i) ok &= ((uint32_t)(hv[i] >> 32) >= tgt); \
                if (ok || ++spin > 2000) break;                                     \
                ld64B_agent(hgr, hv);                                               \
            }                                                                       \
            _Pragma("unroll")                                                       \
            for (int i = 0; i < 8; ++i) {                                           \
                uint32_t pr = (uint32_t)hv[i];                                      \
                int k0 = d0 + 2 * i;                                                \
                int kk = k0 >> 5, off = k0 & 31;                                    \
                int q = (off & 15) >> 2, hi = off >> 4;                             \
                int slot = (m_s + 16 * q) ^ ((2 * kk) & 63);                        \
                *(uint32_t*)((uint8_t*)hx + kk * 1024 + slot * 16 + hi * 8          \
                             + ((off & 3) << 1)) = pr;                              \
            }                                                                       \
        }                                                                           \
        _Pragma("unroll")                                                           \
        for (int tl = 0; tl < 4; ++tl)                                              \
            ACC_N[tl] = (f32x4){bias[tl], bias[tl], bias[tl], bias[tl]};            \
        _Pragma("unroll")                                                           \
        for (int kx = 0; kx < 8; ++kx) {                                            \
            half8 a = __builtin_bit_cast(half8, afx[kx]);                           \
            _Pragma("unroll")                                                       \
            for (int tl = 0; tl < 4; ++tl)                                          \
                ACC_N[tl] = __builtin_amdgcn_mfma_f32_16x16x32_f16(                 \
                    a, __builtin_bit_cast(half8, wf[tl][kx + 8]), ACC_N[tl],        \
                    0, 0, 0);                                                       \
        }                                                                           \
        BARLG();                                                                    \
    }                                                                               \
} while (0)

    for (int t = 0; t < LSTM_T; t += 2) {
        STEP(t,     0, accA, accB);
        STEP(t + 1, 1, accB, accA);
    }
#undef STEP

    if (m_ew < 8) {
        #pragma unroll
        for (int tl = 0; tl < 4; ++tl) {
            int gb = 8 * g + m_ew;
            out[gb * LSTM_H + jj[tl]]                   = hst[tl];
            out[LSTM_B * LSTM_H + gb * LSTM_H + jj[tl]] = cst[tl];
        }
    }
}

extern "C" void kernel_launch(void* const* d_in, const int* in_sizes, int n_in,
                              void* d_out, int out_size, void* d_ws, size_t ws_size,
                              hipStream_t stream) {
    const float* xs   = (const float*)d_in[0];  // [64,4096,256]
    const float* W_ih = (const float*)d_in[1];  // [1024,256]
    const float* W_hh = (const float*)d_in[2];  // [1024,256]
    const float* b    = (const float*)d_in[3];  // [1024]
    float* out = (float*)d_out;
    uint8_t* ws = (uint8_t*)d_ws;

    prep_frags<<<256, 256, 0, stream>>>(W_ih, W_hh, ws);

    const size_t per_t = 131072;   // xg bytes per timestep (4 groups)
    int CH = 0;
    if      (ws_size >= (size_t)WS_XG + 4096 * per_t) CH = 4096;
    else if (ws_size >= (size_t)WS_XG + 1024 * per_t) CH = 1024;
    else if (ws_size >= (size_t)WS_XG +  256 * per_t) CH = 256;

    if (CH) {
        for (int tb = 0; tb < LSTM_T; tb += CH) {
            xg_prep<<<32, 256, 0, stream>>>(xs, b, ws, tb, CH);
            lstm_rec<<<4, 512, 0, stream>>>(ws, out, CH, (tb + CH == LSTM_T) ? 1 : 0);
        }
    } else {
        lstm_r15<<<32, 256, 0, stream>>>(xs, b, ws, out);
    }
}

// Round 14
// 23221.574 us; speedup vs baseline: 1.3623x; 1.3623x over previous
//
#include <hip/hip_runtime.h>
#include <hip/hip_fp16.h>
#include <stdint.h>

// LSTM_29042568856007: B=64, T=4096, D=256, H=256.
// Round 18: R17 family (verified correct) with residency made un-defeatable.
// R17 rec = 6.93us/step with VGPR_Count=128 => the "+v" pin remat'd again
// (R5/R6 disease): weights re-streamed ~384KB/step from L2 (~100GB/s/CU =
// ~3.7us) + xg stalls + weak overlap = 6.9us. Fixes:
//   (1) "+a" (AGPR) pins: global loads can't target AGPRs -> remat is
//       impossible; 128 AGPRs for kk0..3, frees VGPR budget (unified 256).
//   (2) tiers: kk0-3 AGPR (256KB/CU), kk4-5 LDS (128KB), kk6-7 streamed
//       (128KB/step, was 192+). Quarter-passes (2 tiles) cap VGPRs ~111.
//   (3) xg(t+1) reload issued right after last xgv use -> full-step cover.
//   (4) xg_prep split 8x over T (grid 256): ~3.2ms -> ~0.5ms.
// R15 fallback (verified 11.8ms) kept for small-ws.

#define LSTM_B 64
#define LSTM_T 4096
#define LSTM_D 256
#define LSTM_H 256

#define WS_HG_OFF 0x100000u              // R15 fallback hg, 128 KB
#define WS_HST    0x120000u              // h state u32 [4g][16m][128], 32 KB
#define WS_CST    0x128000u              // c state f32 [4g][16m][256], 64 KB
#define WS_XG     0x200000u              // xg f16 pairs, CH*128 KB

typedef __attribute__((ext_vector_type(8))) _Float16 half8;
typedef __attribute__((ext_vector_type(4))) float f32x4;
typedef __attribute__((ext_vector_type(4))) uint32_t u32x4;

#define AST64(p, v) __hip_atomic_store((p), (v), __ATOMIC_RELAXED, __HIP_MEMORY_SCOPE_AGENT)
#define BARLG()     asm volatile("s_waitcnt lgkmcnt(0)\n\ts_barrier" ::: "memory")

static __device__ __forceinline__ float sigmoidf_(float x) {
    return 1.0f / (1.0f + __expf(-x));
}
static __device__ __forceinline__ float tanhf_(float x) {
    float ax = fabsf(x);
    float e  = __expf(-2.0f * ax);
    float t  = (1.0f - e) / (1.0f + e);
    return copysignf(t, x);
}

// ws frags: uint4 frag[T=64][kk=16][lane=64]; layout verified R9..R17.
// slot n = T*16 + (lane&15); source gate row r = (n&3)*256 + (n>>2);
// k = 32*kk + 4*(lane>>4) + (j&3) + 16*(j>>2); k<256 -> W_hh else W_ih.
__global__ __launch_bounds__(256) void prep_frags(
    const float* __restrict__ W_ih, const float* __restrict__ W_hh,
    uint8_t* __restrict__ ws)
{
    int idx = blockIdx.x * blockDim.x + threadIdx.x;   // [0, 65536)
    uint4* Wp = (uint4*)ws;
    int lane = idx & 63;
    int kk   = (idx >> 6) & 15;
    int T    = idx >> 10;
    int n  = T * 16 + (lane & 15);
    int r  = ((n & 3) << 8) + (n >> 2);
    int kb = 32 * kk + 4 * (lane >> 4);
    uint32_t u[4];
    #pragma unroll
    for (int h = 0; h < 4; ++h) {
        uint32_t lohi[2];
        #pragma unroll
        for (int e = 0; e < 2; ++e) {
            int j = 2 * h + e;
            int k = kb + (j & 3) + 16 * (j >> 2);
            float v = (k < 256) ? W_hh[r * 256 + k] : W_ih[r * 256 + (k - 256)];
            lohi[e] = (uint32_t)__half_as_ushort(__float2half(v));
        }
        u[h] = lohi[0] | (lohi[1] << 16);
    }
    Wp[idx] = make_uint4(u[0], u[1], u[2], u[3]);
    if (idx < 32768) ((uint32_t*)(ws + WS_HG_OFF))[idx] = 0u;  // R15 hg
    if (idx < 24576) ((uint32_t*)(ws + WS_HST))[idx]   = 0u;  // h+c state
}

// ============ prepass: xg[t][T][lane], split 8x over T ===================
// grid 256 = gg(4 groups) x cs(8 tile-slices) x ts(8 time-slices), 256 thr.
__global__ __launch_bounds__(256, 1) void xg_prep(
    const float* __restrict__ xs, const float* __restrict__ bias_g,
    uint8_t* __restrict__ ws, int tbase, int CH)
{
    const int tid = threadIdx.x;
    const int l   = tid & 63;
    const int wv  = tid >> 6;            // 0..3
    const int gg  = blockIdx.x >> 6;
    const int cs  = (blockIdx.x >> 3) & 7;
    const int ts  = blockIdx.x & 7;      // time-slice
    const int T0  = cs * 8 + wv * 2;     // this wave: tiles T0, T0+1
    const int CHS = CH >> 3;             // steps per time-slice
    const int t0  = ts * CHS;            // chunk-local start

    const uint4* WF = (const uint4*)ws;
    uint2* xg = (uint2*)(ws + WS_XG) + (size_t)gg * CH * 64 * 64;

    __shared__ __align__(16) uint8_t hxp[8 * 64 * 16];   // x A-frags, 8 KB

    // W_ih B-frags (kk 8..15 of Wp) for 2 tiles: 64 regs, AGPR-pinned
    uint4 wfx[2][8];
    #pragma unroll
    for (int t2 = 0; t2 < 2; ++t2)
        #pragma unroll
        for (int kk = 0; kk < 8; ++kk)
            wfx[t2][kk] = WF[((T0 + t2) * 16 + 8 + kk) * 64 + l];
    #pragma unroll
    for (int t2 = 0; t2 < 2; ++t2)
        #pragma unroll
        for (int kk = 0; kk < 8; ++kk)
            asm volatile("" : "+a"(wfx[t2][kk].x), "+a"(wfx[t2][kk].y),
                              "+a"(wfx[t2][kk].z), "+a"(wfx[t2][kk].w));

    float biasv[2];
    #pragma unroll
    for (int t2 = 0; t2 < 2; ++t2) {
        int slot = (T0 + t2) * 16 + (l & 15);
        biasv[t2] = bias_g[((slot & 3) << 8) + (slot >> 2)];
    }

    // x staging: thread covers (m_s in [0,16), cols d0..d0+15)
    const int m_s = tid >> 4;
    const int d0  = (tid & 15) * 16;
    const float* xrow = xs + (size_t)(16 * gg + m_s) * LSTM_T * LSTM_D + d0;

    float4 xb[4];
    #pragma unroll
    for (int i = 0; i < 4; ++i)
        xb[i] = ((const float4*)(xrow + (size_t)(tbase + t0) * LSTM_D))[i];

    for (int ti = 0; ti < CHS; ++ti) {
        const int tloc = t0 + ti;
        // stage x(t) A-frags (verified swizzle; k0 = d0+4i, kk in [0,8))
        #pragma unroll
        for (int i = 0; i < 4; ++i) {
            float4 xv = xb[i];
            __half2 h0 = __floats2half2_rn(xv.x, xv.y);
            __half2 h1 = __floats2half2_rn(xv.z, xv.w);
            uint64_t v = (uint64_t)__builtin_bit_cast(uint32_t, h0)
                       | ((uint64_t)__builtin_bit_cast(uint32_t, h1) << 32);
            int k0 = d0 + 4 * i;
            int kk = k0 >> 5, off = k0 & 31;
            int q = (off & 15) >> 2, hi = off >> 4;
            int slot = (m_s + 16 * q) ^ ((2 * kk) & 63);
            *(uint64_t*)(hxp + kk * 1024 + slot * 16 + hi * 8) = v;
        }
        {   // prefetch next t (clamped)
            int tn = tbase + tloc + 1; if (tn > LSTM_T - 1) tn = LSTM_T - 1;
            const float4* nx = (const float4*)(xrow + (size_t)tn * LSTM_D);
            #pragma unroll
            for (int i = 0; i < 4; ++i) xb[i] = nx[i];
        }
        BARLG();

        uint4 af[8];
        #pragma unroll
        for (int kk = 0; kk < 8; ++kk)
            af[kk] = *(const uint4*)(hxp + (kk * 64 + (l ^ ((2 * kk) & 63))) * 16);

        f32x4 acc[2];
        #pragma unroll
        for (int t2 = 0; t2 < 2; ++t2)
            acc[t2] = (f32x4){biasv[t2], biasv[t2], biasv[t2], biasv[t2]};
        #pragma unroll
        for (int kk = 0; kk < 8; ++kk) {
            half8 a = __builtin_bit_cast(half8, af[kk]);
            #pragma unroll
            for (int t2 = 0; t2 < 2; ++t2)
                acc[t2] = __builtin_amdgcn_mfma_f32_16x16x32_f16(
                    a, __builtin_bit_cast(half8, wfx[t2][kk]), acc[t2], 0, 0, 0);
        }
        #pragma unroll
        for (int t2 = 0; t2 < 2; ++t2) {
            __half2 lo = __floats2half2_rn(acc[t2].x, acc[t2].y);
            __half2 hi = __floats2half2_rn(acc[t2].z, acc[t2].w);
            xg[(((size_t)tloc) * 64 + T0 + t2) * 64 + l] =
                make_uint2(__builtin_bit_cast(uint32_t, lo),
                           __builtin_bit_cast(uint32_t, hi));
        }
        BARLG();   // hxp reusable
    }
}

// ======== recurrence: 4 WGs x 16 batches; W_hh: AGPR+LDS+small stream =====
__global__ __launch_bounds__(512, 2) void lstm_rec(
    uint8_t* __restrict__ ws, float* __restrict__ out, int CH, int final_ch)
{
    const int tid = threadIdx.x;
    const int l   = tid & 63;
    const int wv  = tid >> 6;            // wave 0..7, owns tiles 8wv..8wv+7
    const int gg  = blockIdx.x;          // batches 16gg..16gg+15

    const uint4* WF = (const uint4*)ws;
    uint32_t* hstate = (uint32_t*)(ws + WS_HST) + (size_t)gg * 16 * 128;
    float*    cstate = (float*)(ws + WS_CST)    + (size_t)gg * 16 * 256;
    const uint2* xg  = (const uint2*)(ws + WS_XG) + (size_t)gg * CH * 64 * 64;

    __shared__ uint4 wl[2 * 64 * 64];                 // W_hh kk4,5: 128 KB
    __shared__ __align__(16) uint8_t hA[8 * 64 * 16]; // h A-frags: 8 KB

    // LDS tier (kk 4..5): 512 thr x 16 uint4
    #pragma unroll
    for (int j2 = 0; j2 < 16; ++j2) {
        int idx = j2 * 512 + tid;        // (kkL*64 + T)*64 + l
        int kkL = idx >> 12, T = (idx >> 6) & 63, ll = idx & 63;
        wl[idx] = WF[(T * 16 + 4 + kkL) * 64 + ll];
    }

    // AGPR tier (kk 0..3) for this wave's 8 tiles: 128 AGPRs, un-remat-able
    uint4 wfh[8][4];
    #pragma unroll
    for (int tl = 0; tl < 8; ++tl) {
        int T = wv * 8 + tl;
        #pragma unroll
        for (int kk = 0; kk < 4; ++kk)
            wfh[tl][kk] = WF[(T * 16 + kk) * 64 + l];
    }
    #pragma unroll
    for (int tl = 0; tl < 8; ++tl)
        #pragma unroll
        for (int kk = 0; kk < 4; ++kk)
            asm volatile("" : "+a"(wfh[tl][kk].x), "+a"(wfh[tl][kk].y),
                              "+a"(wfh[tl][kk].z), "+a"(wfh[tl][kk].w));

    // per-lane ew constants (verified D layout)
    const int  c2   = l & 3;
    const int  qa   = l >> 4;
    const bool c2b0 = (c2 & 1) != 0, c2b1 = (c2 & 2) != 0;
    const int  m_ew = 4 * qa + c2;       // batch row in [0,16)
    int jj[8];
    #pragma unroll
    for (int tl = 0; tl < 8; ++tl) {
        int slot = (wv * 8 + tl) * 16 + (l & 15);
        jj[tl] = slot >> 2;              // h-col [0,256)
    }

    // restore h(t0) into hA (verified scatter)
    if (tid < 256) {
        int m_s = tid >> 4, d0 = (tid & 15) * 16;
        const uint32_t* hr = hstate + m_s * 128 + (d0 >> 1);
        #pragma unroll
        for (int i = 0; i < 8; ++i) {
            uint32_t pr = hr[i];
            int k0 = d0 + 2 * i;
            int kk = k0 >> 5, off = k0 & 31;
            int q = (off & 15) >> 2, hi = off >> 4;
            int slot = (m_s + 16 * q) ^ ((2 * kk) & 63);
            *(uint32_t*)(hA + kk * 1024 + slot * 16 + hi * 8 + ((off & 3) << 1)) = pr;
        }
    }
    float c[8];
    #pragma unroll
    for (int tl = 0; tl < 8; ++tl) c[tl] = cstate[m_ew * 256 + jj[tl]];

    BARLG();   // wl + hA ready

    // prologue: xg(0)
    uint2 xgv[8];
    #pragma unroll
    for (int tl = 0; tl < 8; ++tl)
        xgv[tl] = xg[((size_t)0 * 64 + wv * 8 + tl) * 64 + l];

    uint32_t hpair[8];

    for (int tloc = 0; tloc < CH; ++tloc) {
        // A-frags h(t)
        uint4 af[8];
        #pragma unroll
        for (int kk = 0; kk < 8; ++kk)
            af[kk] = *(const uint4*)(hA + (kk * 64 + (l ^ ((2 * kk) & 63))) * 16);

        const bool fin = final_ch && (tloc == CH - 1);

        // four quarter-passes of 2 tiles (caps live VGPRs ~111)
        #pragma unroll
        for (int qp = 0; qp < 4; ++qp) {
            const int base = qp * 2;
            // streamed tier kk6,7 for these 2 tiles (L2-resident weights)
            uint4 s6[2], s7[2];
            #pragma unroll
            for (int i = 0; i < 2; ++i) {
                int T = wv * 8 + base + i;
                s6[i] = WF[(T * 16 + 6) * 64 + l];
                s7[i] = WF[(T * 16 + 7) * 64 + l];
            }
            // acc init from xg
            f32x4 acc[2];
            #pragma unroll
            for (int i = 0; i < 2; ++i) {
                uint2 v = xgv[base + i];
                float2 f0 = __half22float2(__builtin_bit_cast(__half2, v.x));
                float2 f1 = __half22float2(__builtin_bit_cast(__half2, v.y));
                acc[i] = (f32x4){f0.x, f0.y, f1.x, f1.y};
            }
            // xg(t+1) reload right after last consumption: full-step cover
            if (qp == 3) {
                int tn = (tloc + 1 < CH) ? tloc + 1 : tloc;
                #pragma unroll
                for (int tl = 0; tl < 8; ++tl)
                    xgv[tl] = xg[((size_t)tn * 64 + wv * 8 + tl) * 64 + l];
            }
            // AGPR tier kk0..3
            #pragma unroll
            for (int kk = 0; kk < 4; ++kk) {
                half8 a = __builtin_bit_cast(half8, af[kk]);
                #pragma unroll
                for (int i = 0; i < 2; ++i)
                    acc[i] = __builtin_amdgcn_mfma_f32_16x16x32_f16(
                        a, __builtin_bit_cast(half8, wfh[base + i][kk]), acc[i], 0, 0, 0);
            }
            // LDS tier kk4,5
            #pragma unroll
            for (int kkL = 0; kkL < 2; ++kkL) {
                half8 a = __builtin_bit_cast(half8, af[4 + kkL]);
                #pragma unroll
                for (int i = 0; i < 2; ++i) {
                    uint4 wb = wl[(kkL * 64 + wv * 8 + base + i) * 64 + l];
                    acc[i] = __builtin_amdgcn_mfma_f32_16x16x32_f16(
                        a, __builtin_bit_cast(half8, wb), acc[i], 0, 0, 0);
                }
            }
            // streamed tier kk6,7
            {
                half8 a6 = __builtin_bit_cast(half8, af[6]);
                half8 a7 = __builtin_bit_cast(half8, af[7]);
                #pragma unroll
                for (int i = 0; i < 2; ++i)
                    acc[i] = __builtin_amdgcn_mfma_f32_16x16x32_f16(
                        a6, __builtin_bit_cast(half8, s6[i]), acc[i], 0, 0, 0);
                #pragma unroll
                for (int i = 0; i < 2; ++i)
                    acc[i] = __builtin_amdgcn_mfma_f32_16x16x32_f16(
                        a7, __builtin_bit_cast(half8, s7[i]), acc[i], 0, 0, 0);
            }
            // ew (verified gather) + pack
            #pragma unroll
            for (int i = 0; i < 2; ++i) {
                int tl = base + i;
                f32x4 a = acc[i];
                float s01  = c2b0 ? a.y : a.x;
                float s23  = c2b0 ? a.w : a.z;
                float s01b = c2b0 ? a.x : a.y;
                float s23b = c2b0 ? a.z : a.w;
                float own = c2b1 ? s23  : s01;
                float v1  = c2b1 ? s23b : s01b;
                float v2  = c2b1 ? s01  : s23;
                float v3  = c2b1 ? s01b : s23b;
                float r1 = __shfl_xor(v1, 1, 64);
                float r2 = __shfl_xor(v2, 2, 64);
                float r3 = __shfl_xor(v3, 3, 64);
                float gi = c2b1 ? (c2b0 ? r3 : r2) : (c2b0 ? r1 : own);
                float gf = c2b1 ? (c2b0 ? r2 : r3) : (c2b0 ? own : r1);
                float gg2 = c2b1 ? (c2b0 ? r1 : own) : (c2b0 ? r3 : r2);
                float go = c2b1 ? (c2b0 ? own : r1) : (c2b0 ? r2 : r3);
                float cc = c[tl];
                cc = sigmoidf_(gf) * cc + sigmoidf_(gi) * tanhf_(gg2);
                float hh = sigmoidf_(go) * tanhf_(cc);
                c[tl] = cc;
                uint32_t u  = (uint32_t)__half_as_ushort(__float2half(hh));
                uint32_t up = (uint32_t)__shfl_xor((int)u, 4, 64);
                hpair[tl] = (u & 0xffffu) | (up << 16);
                if (fin) {
                    int b = 16 * gg + m_ew;
                    out[b * LSTM_H + jj[tl]]                   = hh;
                    out[LSTM_B * LSTM_H + b * LSTM_H + jj[tl]] = cc;
                }
            }
        }

        BARLG();   // all A-reads of h(t) complete
        // write h(t+1) into hA (same scatter math, m=m_ew, k0=jj even)
        if ((l & 4) == 0) {
            #pragma unroll
            for (int tl = 0; tl < 8; ++tl) {
                int k0 = jj[tl];
                int kk = k0 >> 5, off = k0 & 31;
                int q = (off & 15) >> 2, hi = off >> 4;
                int slot = (m_ew + 16 * q) ^ ((2 * kk) & 63);
                *(uint32_t*)(hA + kk * 1024 + slot * 16 + hi * 8 + ((off & 3) << 1)) = hpair[tl];
            }
        }
        BARLG();   // h(t+1) visible
    }

    // save state for next chunk
    if ((l & 4) == 0) {
        #pragma unroll
        for (int tl = 0; tl < 8; ++tl)
            hstate[m_ew * 128 + (jj[tl] >> 1)] = hpair[tl];
    }
    #pragma unroll
    for (int tl = 0; tl < 8; ++tl) cstate[m_ew * 256 + jj[tl]] = c[tl];
}

// ===================== R15 fallback (verified, 11.8 ms) ====================
static __device__ __forceinline__ void ld64B_agent(const uint64_t* p, uint64_t* v) {
    u32x4 a, b, cq, d;
    asm volatile(
        "global_load_dwordx4 %0, %4, off sc1\n\t"
        "global_load_dwordx4 %1, %4, off offset:16 sc1\n\t"
        "global_load_dwordx4 %2, %4, off offset:32 sc1\n\t"
        "global_load_dwordx4 %3, %4, off offset:48 sc1\n\t"
        "s_waitcnt vmcnt(0)"
        : "=&v"(a), "=&v"(b), "=&v"(cq), "=&v"(d)
        : "v"(p) : "memory");
    v[0] = ((uint64_t)a.y << 32) | a.x;   v[1] = ((uint64_t)a.w << 32) | a.z;
    v[2] = ((uint64_t)b.y << 32) | b.x;   v[3] = ((uint64_t)b.w << 32) | b.z;
    v[4] = ((uint64_t)cq.y << 32) | cq.x; v[5] = ((uint64_t)cq.w << 32) | cq.z;
    v[6] = ((uint64_t)d.y << 32) | d.x;   v[7] = ((uint64_t)d.w << 32) | d.z;
}

__global__ __launch_bounds__(256, 1) void lstm_r15(
    const float* __restrict__ xs, const float* __restrict__ bias_g,
    uint8_t* __restrict__ ws, float* __restrict__ out)
{
    const int tid = threadIdx.x;
    const int l   = tid & 63;
    const int w   = tid >> 6;
    const int g   = blockIdx.x & 7;
    const int p   = blockIdx.x >> 3;

    const uint4* WF = (const uint4*)ws;
    uint64_t* hg64  = (uint64_t*)(ws + WS_HG_OFF);

    __shared__ uint4 hx[16 * 64];

    uint4 wf[4][16];
    #pragma unroll
    for (int tl = 0; tl < 4; ++tl) {
        int T = p * 16 + w * 4 + tl;
        #pragma unroll
        for (int kk = 0; kk < 16; ++kk)
            wf[tl][kk] = WF[(T * 16 + kk) * 64 + l];
    }
    #pragma unroll
    for (int tl = 0; tl < 4; ++tl)
        #pragma unroll
        for (int kk = 0; kk < 16; ++kk)
            asm volatile("" : "+v"(wf[tl][kk].x), "+v"(wf[tl][kk].y),
                              "+v"(wf[tl][kk].z), "+v"(wf[tl][kk].w));

    const int  c2   = l & 3;
    const int  qa   = l >> 4;
    const bool c2b0 = (c2 & 1) != 0, c2b1 = (c2 & 2) != 0;
    const int  m_ew = 4 * qa + c2;
    float bias[4];
    int   jj[4];
    #pragma unroll
    for (int tl = 0; tl < 4; ++tl) {
        int T    = p * 16 + w * 4 + tl;
        int slot = T * 16 + (l & 15);
        int r    = ((slot & 3) << 8) + (slot >> 2);
        bias[tl] = bias_g[r];
        jj[tl]   = slot >> 2;
    }

    const int m_s = tid >> 4;
    const int d0  = (tid & 15) * 16;
    const float* xrow = xs + (size_t)(8 * g + (m_s & 7)) * LSTM_T * LSTM_D + d0;

    hx[tid]       = make_uint4(0, 0, 0, 0);
    hx[tid + 256] = make_uint4(0, 0, 0, 0);
    hx[tid + 512] = make_uint4(0, 0, 0, 0);
    hx[tid + 768] = make_uint4(0, 0, 0, 0);
    float4 xb[2][4];
    if (m_s < 8) {
        #pragma unroll
        for (int i = 0; i < 4; ++i) {
            float4 xv = ((const float4*)xrow)[i];
            __half2 h0 = __floats2half2_rn(xv.x, xv.y);
            __half2 h1 = __floats2half2_rn(xv.z, xv.w);
            uint64_t v = (uint64_t)__builtin_bit_cast(uint32_t, h0)
                       | ((uint64_t)__builtin_bit_cast(uint32_t, h1) << 32);
            int k0 = 256 + d0 + 4 * i;
            int kk = k0 >> 5, off = k0 & 31;
            int q = (off & 15) >> 2, hi = off >> 4;
            int slot = (m_s + 16 * q) ^ ((2 * kk) & 63);
            *(uint64_t*)((uint8_t*)hx + kk * 1024 + slot * 16 + hi * 8) = v;
        }
        #pragma unroll
        for (int i = 0; i < 4; ++i) xb[0][i] = ((const float4*)(xrow + (size_t)1 * LSTM_D))[i];
        #pragma unroll
        for (int i = 0; i < 4; ++i) xb[1][i] = ((const float4*)(xrow + (size_t)2 * LSTM_D))[i];
    }
    BARLG();

    f32x4 accA[4], accB[4];
    {
        uint4 afx[8];
        #pragma unroll
        for (int kx = 0; kx < 8; ++kx) {
            int kk = kx + 8;
            afx[kx] = hx[kk * 64 + (l ^ ((2 * kk) & 63))];
        }
        #pragma unroll
        for (int tl = 0; tl < 4; ++tl)
            accA[tl] = (f32x4){bias[tl], bias[tl], bias[tl], bias[tl]};
        #pragma unroll
        for (int kx = 0; kx < 8; ++kx) {
            half8 a = __builtin_bit_cast(half8, afx[kx]);
            #pragma unroll
            for (int tl = 0; tl < 4; ++tl)
                accA[tl] = __builtin_amdgcn_mfma_f32_16x16x32_f16(
                    a, __builtin_bit_cast(half8, wf[tl][kx + 8]), accA[tl], 0, 0, 0);
        }
    }

    float cst[4] = {0, 0, 0, 0}, hst[4] = {0, 0, 0, 0};

#define STEP(T_, PAR, ACC_C, ACC_N) do {                                            \
    uint4 afh[8];                                                                   \
    _Pragma("unroll")                                                               \
    for (int kk = 0; kk < 8; ++kk)                                                  \
        afh[kk] = hx[kk * 64 + (l ^ ((2 * kk) & 63))];                              \
    _Pragma("unroll")                                                               \
    for (int kk = 0; kk < 8; ++kk) {                                                \
        half8 a = __builtin_bit_cast(half8, afh[kk]);                               \
        _Pragma("unroll")                                                           \
        for (int tl = 0; tl < 4; ++tl)                                              \
            ACC_C[tl] = __builtin_amdgcn_mfma_f32_16x16x32_f16(                     \
                a, __builtin_bit_cast(half8, wf[tl][kk]), ACC_C[tl], 0, 0, 0);      \
    }                                                                               \
    uint32_t hpair[4];                                                              \
    _Pragma("unroll")                                                               \
    for (int tl = 0; tl < 4; ++tl) {                                                \
        f32x4 a = ACC_C[tl];                                                        \
        float s01  = c2b0 ? a.y : a.x;                                              \
        float s23  = c2b0 ? a.w : a.z;                                              \
        float s01b = c2b0 ? a.x : a.y;                                              \
        float s23b = c2b0 ? a.z : a.w;                                              \
        float own = c2b1 ? s23  : s01;                                              \
        float v1  = c2b1 ? s23b : s01b;                                             \
        float v2  = c2b1 ? s01  : s23;                                              \
        float v3  = c2b1 ? s01b : s23b;                                             \
        float r1 = __shfl_xor(v1, 1, 64);                                           \
        float r2 = __shfl_xor(v2, 2, 64);                                           \
        float r3 = __shfl_xor(v3, 3, 64);                                           \
        float gi = c2b1 ? (c2b0 ? r3 : r2) : (c2b0 ? r1 : own);                     \
        float gf = c2b1 ? (c2b0 ? r2 : r3) : (c2b0 ? own : r1);                     \
        float gg = c2b1 ? (c2b0 ? r1 : own) : (c2b0 ? r3 : r2);                     \
        float go = c2b1 ? (c2b0 ? own : r1) : (c2b0 ? r2 : r3);                     \
        float cc = cst[tl];                                                         \
        cc = sigmoidf_(gf) * cc + sigmoidf_(gi) * tanhf_(gg);                       \
        float hh = sigmoidf_(go) * tanhf_(cc);                                      \
        cst[tl] = cc; hst[tl] = hh;                                                 \
        uint32_t u  = (uint32_t)__half_as_ushort(__float2half(hh));                 \
        uint32_t up = (uint32_t)__shfl_xor((int)u, 4, 64);                          \
        hpair[tl] = (u & 0xffffu) | (up << 16);                                     \
    }                                                                               \
    {                                                                               \
        const int buf = (PAR) ^ 1;                                                  \
        if (l < 32 && (l & 4) == 0) {                                               \
            uint64_t* hgrow = hg64 + (((size_t)g * 2 + buf) * 8 + m_ew) * 128;      \
            const uint64_t tagw = ((uint64_t)(uint32_t)(T_ + 1)) << 32;             \
            _Pragma("unroll")                                                       \
            for (int tl = 0; tl < 4; ++tl)                                          \
                AST64(&hgrow[jj[tl] >> 1], tagw | (uint64_t)hpair[tl]);             \
        }                                                                           \
        if (m_s < 8) {                                                              \
            _Pragma("unroll")                                                       \
            for (int i = 0; i < 4; ++i) {                                           \
                float4 xv = xb[PAR][i];                                             \
                __half2 h0 = __floats2half2_rn(xv.x, xv.y);                         \
                __half2 h1 = __floats2half2_rn(xv.z, xv.w);                         \
                uint64_t v = (uint64_t)__builtin_bit_cast(uint32_t, h0)             \
                           | ((uint64_t)__builtin_bit_cast(uint32_t, h1) << 32);    \
                int k0 = 256 + d0 + 4 * i;                                          \
                int kk = k0 >> 5, off = k0 & 31;                                    \
                int q = (off & 15) >> 2, hi = off >> 4;                             \
                int slot = (m_s + 16 * q) ^ ((2 * kk) & 63);                        \
                *(uint64_t*)((uint8_t*)hx + kk * 1024 + slot * 16 + hi * 8) = v;    \
            }                                                                       \
            int tn = (T_ + 3 < LSTM_T) ? T_ + 3 : T_;                               \
            const float4* nx = (const float4*)(xrow + (size_t)tn * LSTM_D);         \
            _Pragma("unroll")                                                       \
            for (int i = 0; i < 4; ++i) xb[PAR][i] = nx[i];                         \
        }                                                                           \
        BARLG();                                                                    \
        uint4 afx[8];                                                               \
        _Pragma("unroll")                                                           \
        for (int kx = 0; kx < 8; ++kx) {                                            \
            int kk = kx + 8;                                                        \
            afx[kx] = hx[kk * 64 + (l ^ ((2 * kk) & 63))];                          \
        }                                                                           \
        if (m_s < 8) {                                                              \
            const uint32_t tgt = (uint32_t)(T_ + 1);                                \
            uint64_t* hgr = hg64 + (((size_t)g * 2 + buf) * 8 + m_s) * 128          \
                          + (d0 >> 1);                                              \
            uint64_t hv[8];                                                         \
            ld64B_agent(hgr, hv);                                                   \
            int spin = 0;                                                           \
            while (true) {                                                          \
                bool ok = true;                                                     \
                _Pragma("unroll")                                                   \
                for (int i = 0; i < 8; ++i) ok &= ((uint32_t)(hv[i] >> 32) >= tgt); \
                if (ok || ++spin > 2000) break;                                     \
                ld64B_agent(hgr, hv);                                               \
            }                                                                       \
            _Pragma("unroll")                                                       \
            for (int i = 0; i < 8; ++i) {                                           \
                uint32_t pr = (uint32_t)hv[i];                                      \
                int k0 = d0 + 2 * i;                                                \
                int kk = k0 >> 5, off = k0 & 31;                                    \
                int q = (off & 15) >> 2, hi = off >> 4;                             \
                int slot = (m_s + 16 * q) ^ ((2 * kk) & 63);                        \
                *(uint32_t*)((uint8_t*)hx + kk * 1024 + slot * 16 + hi * 8          \
                             + ((off & 3) << 1)) = pr;                              \
            }                                                                       \
        }                                                                           \
        _Pragma("unroll")                                                           \
        for (int tl = 0; tl < 4; ++tl)                                              \
            ACC_N[tl] = (f32x4){bias[tl], bias[tl], bias[tl], bias[tl]};            \
        _Pragma("unroll")                                                           \
        for (int kx = 0; kx < 8; ++kx) {                                            \
            half8 a = __builtin_bit_cast(half8, afx[kx]);                           \
            _Pragma("unroll")                                                       \
            for (int tl = 0; tl < 4; ++tl)                                          \
                ACC_N[tl] = __builtin_amdgcn_mfma_f32_16x16x32_f16(                 \
                    a, __builtin_bit_cast(half8, wf[tl][kx + 8]), ACC_N[tl],        \
                    0, 0, 0);                                                       \
        }                                                                           \
        BARLG();                                                                    \
    }                                                                               \
} while (0)

    for (int t = 0; t < LSTM_T; t += 2) {
        STEP(t,     0, accA, accB);
        STEP(t + 1, 1, accB, accA);
    }
#undef STEP

    if (m_ew < 8) {
        #pragma unroll
        for (int tl = 0; tl < 4; ++tl) {
            int gb = 8 * g + m_ew;
            out[gb * LSTM_H + jj[tl]]                   = hst[tl];
            out[LSTM_B * LSTM_H + gb * LSTM_H + jj[tl]] = cst[tl];
        }
    }
}

extern "C" void kernel_launch(void* const* d_in, const int* in_sizes, int n_in,
                              void* d_out, int out_size, void* d_ws, size_t ws_size,
                              hipStream_t stream) {
    const float* xs   = (const float*)d_in[0];  // [64,4096,256]
    const float* W_ih = (const float*)d_in[1];  // [1024,256]
    const float* W_hh = (const float*)d_in[2];  // [1024,256]
    const float* b    = (const float*)d_in[3];  // [1024]
    float* out = (float*)d_out;
    uint8_t* ws = (uint8_t*)d_ws;

    prep_frags<<<256, 256, 0, stream>>>(W_ih, W_hh, ws);

    const size_t per_t = 131072;   // xg bytes per timestep (4 groups)
    int CH = 0;
    if      (ws_size >= (size_t)WS_XG + 4096 * per_t) CH = 4096;
    else if (ws_size >= (size_t)WS_XG + 1024 * per_t) CH = 1024;
    else if (ws_size >= (size_t)WS_XG +  256 * per_t) CH = 256;

    if (CH) {
        for (int tb = 0; tb < LSTM_T; tb += CH) {
            xg_prep<<<256, 256, 0, stream>>>(xs, b, ws, tb, CH);
            lstm_rec<<<4, 512, 0, stream>>>(ws, out, CH, (tb + CH == LSTM_T) ? 1 : 0);
        }
    } else {
        lstm_r15<<<32, 256, 0, stream>>>(xs, b, ws, out);
    }
}